// Round 4
// baseline (624.605 us; speedup 1.0000x reference)
//
#include <hip/hip_runtime.h>
#include <math.h>

// Problem dims (fixed by the reference)
#define ED 16      // EDGE_DIM
#define HD 32      // HIDDEN (== NODE_DIM == in_channels)
#define OD 32      // OUT_DIM
#define KD 1024    // HD*OD
#define EPB 256    // edges per block
#define TPW 4      // 16-edge tiles per wave
#define HPAD 40    // padded LDS row stride (halfwords) for h: optimal banking

typedef float  f32x4  __attribute__((ext_vector_type(4)));
typedef float  v4f    __attribute__((ext_vector_type(4)));
typedef short  bf16x8 __attribute__((ext_vector_type(8)));

// Workspace layout (byte offsets; all 16B aligned)
//  [0)      W1fT   512 f32   [c][j] transposed, bn1-scaled
//  [2048)   b1f     32 f32
//  [2176)   bfold 1024 f32   folded layer-2 bias, natural k order
//  [6272)   wsAhi 32768 bf16 W2fT hi, frag-linear: q = g*512 + lane*8 + idx
//                             -> value W2fT[k=g*16+(lane&15)][j=(lane>>4)*8+idx]
//  [71808)  wsAlo 32768 bf16 W2fT lo, same order
constexpr size_t WS_BYTES = 137344;

__device__ inline void bf16_split(float v, unsigned short& hi, unsigned short& lo) {
    unsigned int b = __float_as_uint(v);
    hi = (unsigned short)(b >> 16);
    float hif = __uint_as_float((unsigned int)hi << 16);
    float lof = v - hif;
    lo = (unsigned short)(__float_as_uint(lof) >> 16);
}

// ---------------------------------------------------------------------------
// Prep: fold BN into weights/biases; write W2fT as hi/lo bf16 in the exact
// per-lane fragment-linear order the edge kernel's A-operand loads use.
// ---------------------------------------------------------------------------
__global__ void prep_kernel(const float* __restrict__ W1, const float* __restrict__ b1,
                            const float* __restrict__ g1, const float* __restrict__ be1,
                            const float* __restrict__ m1, const float* __restrict__ v1,
                            const float* __restrict__ W2, const float* __restrict__ b2,
                            const float* __restrict__ g2, const float* __restrict__ be2,
                            const float* __restrict__ m2, const float* __restrict__ v2,
                            unsigned char* __restrict__ wsb)
{
    float* w1t = (float*)(wsb);
    float* b1f = (float*)(wsb + 2048);
    float* bf  = (float*)(wsb + 2176);
    unsigned short* ahi = (unsigned short*)(wsb + 6272);
    unsigned short* alo = (unsigned short*)(wsb + 71808);

    int t = blockIdx.x * blockDim.x + threadIdx.x;
    int stride = gridDim.x * blockDim.x;

    for (int q = t; q < HD * ED; q += stride) {       // W1fT [c][j]
        int c = q >> 4, j = q & 15;
        float s = g1[c] / sqrtf(v1[c] + 1e-5f);
        w1t[q] = W1[j * HD + c] * s;
    }
    for (int c = t; c < HD; c += stride) {
        float s = g1[c] / sqrtf(v1[c] + 1e-5f);
        b1f[c] = b1[c] * s + be1[c] - m1[c] * s;
    }
    for (int k = t; k < KD; k += stride) {
        float s = g2[k] / sqrtf(v2[k] + 1e-5f);
        bf[k] = b2[k] * s + be2[k] - m2[k] * s;
    }
    for (int q = t; q < KD * HD; q += stride) {       // frag-linear W2fT hi/lo
        int g = q >> 9;
        int r = q & 511;
        int lane = r >> 3, idx = r & 7;
        int m = lane & 15, quad = lane >> 4;
        int k = g * 16 + m;
        int j = quad * 8 + idx;
        float s = g2[k] / sqrtf(v2[k] + 1e-5f);
        float v = W2[j * KD + k] * s;
        unsigned short hi, lo;
        bf16_split(v, hi, lo);
        ahi[q] = hi;
        alo[q] = lo;
    }
}

// ---------------------------------------------------------------------------
// out = x @ root + bias  (initializes all of d_out before edge atomics land)
// ---------------------------------------------------------------------------
__global__ void root_kernel(const float* __restrict__ x, const float* __restrict__ root,
                            const float* __restrict__ bias, float* __restrict__ out, int nN)
{
    int t = blockIdx.x * blockDim.x + threadIdx.x;
    if (t >= nN * OD) return;
    int o = t & (OD - 1);
    int n = t >> 5;
    const float* xr = x + (size_t)n * HD;
    float acc = bias[o];
#pragma unroll
    for (int i = 0; i < HD; ++i)
        acc = fmaf(xr[i], root[i * OD + o], acc);
    out[t] = acc;
}

// ---------------------------------------------------------------------------
// Fused edge kernel v4 (MFMA + explicit software pipeline):
//  Phase 1: one edge/thread -> h (32 regs), hi/lo bf16 pack, ds_write_b128
//           into LDS rows padded to HPAD=40 halfwords (conflict-optimal).
//  Phase 2: C[k][edge] = W2fT[k][:] @ h[:][edge]; A frags double-buffered
//           from global (prefetch i+1 before consuming i), x gathers
//           likewise prefetched, bias from LDS. 3 MFMAs per C (split-bf16).
//  2 barriers/block; 49.3 KB LDS -> 3 blocks/CU; launch_bounds(256,3)
//  allows ~170 VGPRs for the pipeline registers.
// ---------------------------------------------------------------------------
__global__ __launch_bounds__(256, 3)
void edge_kernel(const float* __restrict__ x, const int* __restrict__ eidx,
                 const float* __restrict__ ea_g, const unsigned char* __restrict__ wsb,
                 float* __restrict__ out, int nE)
{
    __shared__ __align__(16) float w1t[512];
    __shared__ __align__(16) float b1s[32];
    __shared__ __align__(16) float bfS[KD];                 // folded layer-2 bias
    __shared__ __align__(16) unsigned short hHi[EPB * HPAD];
    __shared__ __align__(16) unsigned short hLo[EPB * HPAD];
    __shared__ int srcS[EPB];
    __shared__ int dstS[EPB];

    const int t = threadIdx.x;
    const float* wsW1 = (const float*)(wsb);
    const float* wsB1 = (const float*)(wsb + 2048);
    const float* wsBf = (const float*)(wsb + 2176);
    const unsigned short* wsAhi = (const unsigned short*)(wsb + 6272);
    const unsigned short* wsAlo = (const unsigned short*)(wsb + 71808);

    // stage W1fT + b1f + bfold
    if (t < 128)      ((v4f*)w1t)[t] = ((const v4f*)wsW1)[t];
    else if (t < 136) ((v4f*)b1s)[t - 128] = ((const v4f*)wsB1)[t - 128];
    ((v4f*)bfS)[t] = ((const v4f*)wsBf)[t];

    int e = blockIdx.x * EPB + t;
    int ec = (e < nE) ? e : (nE - 1);
    srcS[t] = eidx[ec];
    dstS[t] = eidx[nE + ec];

    const v4f* eap = (const v4f*)(ea_g + (size_t)ec * ED);
    v4f a0 = eap[0], a1 = eap[1], a2 = eap[2], a3 = eap[3];

    __syncthreads();   // w1t/b1s ready

    // ---- layer 1 into registers ----
    float hreg[HD];
#pragma unroll
    for (int c = 0; c < HD; ++c) {
        const v4f* r4 = (const v4f*)(w1t + c * ED);
        v4f w0 = r4[0], w1 = r4[1], w2 = r4[2], w3 = r4[3];
        float acc = b1s[c];
        acc = fmaf(a0.x, w0.x, acc); acc = fmaf(a0.y, w0.y, acc);
        acc = fmaf(a0.z, w0.z, acc); acc = fmaf(a0.w, w0.w, acc);
        acc = fmaf(a1.x, w1.x, acc); acc = fmaf(a1.y, w1.y, acc);
        acc = fmaf(a1.z, w1.z, acc); acc = fmaf(a1.w, w1.w, acc);
        acc = fmaf(a2.x, w2.x, acc); acc = fmaf(a2.y, w2.y, acc);
        acc = fmaf(a2.z, w2.z, acc); acc = fmaf(a2.w, w2.w, acc);
        acc = fmaf(a3.x, w3.x, acc); acc = fmaf(a3.y, w3.y, acc);
        acc = fmaf(a3.z, w3.z, acc); acc = fmaf(a3.w, w3.w, acc);
        hreg[c] = fmaxf(acc, 0.01f * acc);
    }

    // ---- pack hi/lo and store to padded LDS rows (b128, conflict-optimal) --
#pragma unroll
    for (int ch = 0; ch < 4; ++ch) {
        bf16x8 phi, plo;
#pragma unroll
        for (int u = 0; u < 8; ++u) {
            unsigned short hi, lo;
            bf16_split(hreg[ch * 8 + u], hi, lo);
            phi[u] = (short)hi;
            plo[u] = (short)lo;
        }
        *(bf16x8*)(hHi + t * HPAD + ch * 8) = phi;
        *(bf16x8*)(hLo + t * HPAD + ch * 8) = plo;
    }
    __syncthreads();

    // ---- phase 2: MFMA GEMM + fused contraction ----
    const int wave = t >> 6;
    const int lane = t & 63;
    const int n = lane & 15;       // C column = edge within tile
    const int quad = lane >> 4;
    const int ebase = wave * 64;   // wave's first edge in block

    bf16x8 bHi[TPW], bLo[TPW];
#pragma unroll
    for (int tt = 0; tt < TPW; ++tt) {
        int edge = ebase + tt * 16 + n;
        bHi[tt] = *(const bf16x8*)(hHi + edge * HPAD + quad * 8);
        bLo[tt] = *(const bf16x8*)(hLo + edge * HPAD + quad * 8);
    }

    const float* xp[TPW];
    int xdst[TPW];
    bool evalid[TPW];
#pragma unroll
    for (int tt = 0; tt < TPW; ++tt) {
        int le = ebase + tt * 16 + n;
        evalid[tt] = (blockIdx.x * EPB + le) < nE;
        xp[tt] = x + (size_t)srcS[le] * HD;
        xdst[tt] = dstS[le];
    }

    f32x4 msg[TPW][2];
#pragma unroll
    for (int tt = 0; tt < TPW; ++tt) {
        msg[tt][0] = (f32x4){0.f, 0.f, 0.f, 0.f};
        msg[tt][1] = (f32x4){0.f, 0.f, 0.f, 0.f};
    }

    const unsigned short* pAhi = wsAhi + lane * 8;
    const unsigned short* pAlo = wsAlo + lane * 8;

    // prologue: loads for i=0
    bf16x8 cH0 = *(const bf16x8*)(pAhi + 0 * 512);
    bf16x8 cL0 = *(const bf16x8*)(pAlo + 0 * 512);
    bf16x8 cH1 = *(const bf16x8*)(pAhi + 1 * 512);
    bf16x8 cL1 = *(const bf16x8*)(pAlo + 1 * 512);
    float cx[TPW];
#pragma unroll
    for (int tt = 0; tt < TPW; ++tt) cx[tt] = xp[tt][0];

#pragma unroll
    for (int i = 0; i < HD; ++i) {
        // ---- prefetch i+1 (dead on last iteration; compiler prunes) ----
        bf16x8 nH0 = cH0, nL0 = cL0, nH1 = cH1, nL1 = cL1;
        float nx[TPW];
#pragma unroll
        for (int tt = 0; tt < TPW; ++tt) nx[tt] = cx[tt];
        if (i + 1 < HD) {
            const int gn = 2 * (i + 1);
            nH0 = *(const bf16x8*)(pAhi + (size_t)gn * 512);
            nL0 = *(const bf16x8*)(pAlo + (size_t)gn * 512);
            nH1 = *(const bf16x8*)(pAhi + (size_t)(gn + 1) * 512);
            nL1 = *(const bf16x8*)(pAlo + (size_t)(gn + 1) * 512);
#pragma unroll
            for (int tt = 0; tt < TPW; ++tt) nx[tt] = xp[tt][i + 1];
        }

        f32x4 b0 = *(const f32x4*)(bfS + (2 * i) * 16 + quad * 4);
        f32x4 b1v = *(const f32x4*)(bfS + (2 * i + 1) * 16 + quad * 4);

#pragma unroll
        for (int tt = 0; tt < TPW; ++tt) {
            f32x4 c0 = b0;
            c0 = __builtin_amdgcn_mfma_f32_16x16x32_bf16(cL0, bHi[tt], c0, 0, 0, 0);
            c0 = __builtin_amdgcn_mfma_f32_16x16x32_bf16(cH0, bLo[tt], c0, 0, 0, 0);
            c0 = __builtin_amdgcn_mfma_f32_16x16x32_bf16(cH0, bHi[tt], c0, 0, 0, 0);
            f32x4 c1 = b1v;
            c1 = __builtin_amdgcn_mfma_f32_16x16x32_bf16(cL1, bHi[tt], c1, 0, 0, 0);
            c1 = __builtin_amdgcn_mfma_f32_16x16x32_bf16(cH1, bLo[tt], c1, 0, 0, 0);
            c1 = __builtin_amdgcn_mfma_f32_16x16x32_bf16(cH1, bHi[tt], c1, 0, 0, 0);
            f32x4 w0 = __builtin_elementwise_max(c0, 0.01f * c0);   // LeakyReLU
            f32x4 w1 = __builtin_elementwise_max(c1, 0.01f * c1);
            f32x4 xs = {cx[tt], cx[tt], cx[tt], cx[tt]};
            msg[tt][0] = __builtin_elementwise_fma(xs, w0, msg[tt][0]);
            msg[tt][1] = __builtin_elementwise_fma(xs, w1, msg[tt][1]);
        }

        // rotate pipeline registers
        cH0 = nH0; cL0 = nL0; cH1 = nH1; cL1 = nL1;
#pragma unroll
        for (int tt = 0; tt < TPW; ++tt) cx[tt] = nx[tt];
    }

    // ---- scatter: out[dst][o], o = oh*16 + quad*4 + r ----
#pragma unroll
    for (int tt = 0; tt < TPW; ++tt) {
        if (!evalid[tt]) continue;
        float* op = out + (size_t)xdst[tt] * OD;
#pragma unroll
        for (int oh = 0; oh < 2; ++oh)
#pragma unroll
            for (int r = 0; r < 4; ++r)
                atomicAdd(op + oh * 16 + quad * 4 + r, msg[tt][oh][r]);
    }
}

// ---------------------------------------------------------------------------
// Fallback (ws too small): correctness path only (VALU, raw weights).
// ---------------------------------------------------------------------------
__global__ __launch_bounds__(64)
void edge_kernel_raw(const float* __restrict__ x, const int* __restrict__ eidx,
                     const float* __restrict__ ea_g,
                     const float* __restrict__ W1, const float* __restrict__ b1,
                     const float* __restrict__ g1, const float* __restrict__ be1,
                     const float* __restrict__ m1, const float* __restrict__ v1,
                     const float* __restrict__ W2, const float* __restrict__ b2,
                     const float* __restrict__ g2, const float* __restrict__ be2,
                     const float* __restrict__ m2, const float* __restrict__ v2,
                     float* __restrict__ out, int nE)
{
    int e = blockIdx.x * 64 + threadIdx.x;
    if (e >= nE) return;
    const int obase = blockIdx.y * 16;

    int src = eidx[e];
    int dst = eidx[nE + e];

    float ea[ED];
#pragma unroll
    for (int j = 0; j < ED; ++j) ea[j] = ea_g[(size_t)e * ED + j];

    float h[HD];
#pragma unroll
    for (int c = 0; c < HD; ++c) {
        float acc = b1[c];
#pragma unroll
        for (int j = 0; j < ED; ++j) acc = fmaf(ea[j], W1[j * HD + c], acc);
        float s = g1[c] / sqrtf(v1[c] + 1e-5f);
        acc = (acc - m1[c]) * s + be1[c];
        h[c] = fmaxf(acc, 0.01f * acc);
    }

    float msg[16];
#pragma unroll
    for (int o = 0; o < 16; ++o) msg[o] = 0.f;

    const float* xj = x + (size_t)src * HD;
    for (int i = 0; i < HD; ++i) {
        float xv = xj[i];
#pragma unroll
        for (int oo = 0; oo < 16; ++oo) {
            int k = i * OD + obase + oo;
            float acc = b2[k];
#pragma unroll
            for (int j = 0; j < HD; ++j) acc = fmaf(h[j], W2[j * KD + k], acc);
            float s = g2[k] / sqrtf(v2[k] + 1e-5f);
            acc = (acc - m2[k]) * s + be2[k];
            float w = fmaxf(acc, 0.01f * acc);
            msg[oo] = fmaf(xv, w, msg[oo]);
        }
    }

    float* op = out + (size_t)dst * OD + obase;
#pragma unroll
    for (int oo = 0; oo < 16; ++oo) atomicAdd(op + oo, msg[oo]);
}

// ---------------------------------------------------------------------------
extern "C" void kernel_launch(void* const* d_in, const int* in_sizes, int n_in,
                              void* d_out, int out_size, void* d_ws, size_t ws_size,
                              hipStream_t stream)
{
    const float* x    = (const float*)d_in[0];
    const int*   eidx = (const int*)  d_in[1];
    const float* ea   = (const float*)d_in[2];
    // d_in[3] = batch (unused)
    const float* W1   = (const float*)d_in[4];
    const float* b1   = (const float*)d_in[5];
    const float* g1   = (const float*)d_in[6];
    const float* be1  = (const float*)d_in[7];
    const float* m1   = (const float*)d_in[8];
    const float* v1   = (const float*)d_in[9];
    const float* W2   = (const float*)d_in[10];
    const float* b2   = (const float*)d_in[11];
    const float* g2   = (const float*)d_in[12];
    const float* be2  = (const float*)d_in[13];
    const float* m2   = (const float*)d_in[14];
    const float* v2   = (const float*)d_in[15];
    const float* root = (const float*)d_in[16];
    const float* bias = (const float*)d_in[17];
    float* out = (float*)d_out;

    int nN = in_sizes[0] / HD;
    int nE = in_sizes[2] / ED;

    root_kernel<<<dim3((nN * OD + 255) / 256), 256, 0, stream>>>(x, root, bias, out, nN);

    if (ws_size >= WS_BYTES) {
        unsigned char* wsb = (unsigned char*)d_ws;
        prep_kernel<<<128, 256, 0, stream>>>(W1, b1, g1, be1, m1, v1,
                                             W2, b2, g2, be2, m2, v2, wsb);
        int nblk = (nE + EPB - 1) / EPB;
        edge_kernel<<<dim3(nblk), 256, 0, stream>>>(x, eidx, ea, wsb, out, nE);
    } else {
        edge_kernel_raw<<<dim3((nE + 63) / 64, 2), 64, 0, stream>>>(
            x, eidx, ea, W1, b1, g1, be1, m1, v1,
            W2, b2, g2, be2, m2, v2, out, nE);
    }
}

// Round 5
// 250.607 us; speedup vs baseline: 2.4924x; 2.4924x over previous
//
#include <hip/hip_runtime.h>
#include <math.h>

// Problem dims (fixed by the reference)
#define ED 16      // EDGE_DIM
#define HD 32      // HIDDEN (== NODE_DIM == in_channels)
#define OD 32      // OUT_DIM
#define KD 1024    // HD*OD
#define EPB 256    // edges per block
#define TPW 4      // 16-edge tiles per wave
#define HPAD 40    // padded LDS row stride (halfwords) for h (16B-aligned rows)
#define XPAD 33    // padded LDS row stride (floats) for x rows (conflict-free)

typedef float  f32x4  __attribute__((ext_vector_type(4)));
typedef float  v4f    __attribute__((ext_vector_type(4)));
typedef short  bf16x8 __attribute__((ext_vector_type(8)));

// Workspace layout (byte offsets; all 16B aligned)
//  [0)      W1fT   512 f32   [c][j] transposed, bn1-scaled
//  [2048)   b1f     32 f32
//  [2176)   bfold 1024 f32   folded layer-2 bias, natural k order
//  [6272)   wsAhi 32768 bf16 W2fT hi, frag-linear: q = g*512 + lane*8 + idx
//                             -> value W2fT[k=g*16+(lane&15)][j=(lane>>4)*8+idx]
//  [71808)  wsAlo 32768 bf16 W2fT lo, same order
constexpr size_t WS_BYTES = 137344;

__device__ inline void bf16_split(float v, unsigned short& hi, unsigned short& lo) {
    unsigned int b = __float_as_uint(v);
    hi = (unsigned short)(b >> 16);
    float hif = __uint_as_float((unsigned int)hi << 16);
    float lof = v - hif;
    lo = (unsigned short)(__float_as_uint(lof) >> 16);
}

// ---------------------------------------------------------------------------
// Prep: fold BN into weights/biases; write W2fT as hi/lo bf16 in the exact
// per-lane fragment-linear order the edge kernel's A-operand loads use.
// ---------------------------------------------------------------------------
__global__ void prep_kernel(const float* __restrict__ W1, const float* __restrict__ b1,
                            const float* __restrict__ g1, const float* __restrict__ be1,
                            const float* __restrict__ m1, const float* __restrict__ v1,
                            const float* __restrict__ W2, const float* __restrict__ b2,
                            const float* __restrict__ g2, const float* __restrict__ be2,
                            const float* __restrict__ m2, const float* __restrict__ v2,
                            unsigned char* __restrict__ wsb)
{
    float* w1t = (float*)(wsb);
    float* b1f = (float*)(wsb + 2048);
    float* bf  = (float*)(wsb + 2176);
    unsigned short* ahi = (unsigned short*)(wsb + 6272);
    unsigned short* alo = (unsigned short*)(wsb + 71808);

    int t = blockIdx.x * blockDim.x + threadIdx.x;
    int stride = gridDim.x * blockDim.x;

    for (int q = t; q < HD * ED; q += stride) {       // W1fT [c][j]
        int c = q >> 4, j = q & 15;
        float s = g1[c] / sqrtf(v1[c] + 1e-5f);
        w1t[q] = W1[j * HD + c] * s;
    }
    for (int c = t; c < HD; c += stride) {
        float s = g1[c] / sqrtf(v1[c] + 1e-5f);
        b1f[c] = b1[c] * s + be1[c] - m1[c] * s;
    }
    for (int k = t; k < KD; k += stride) {
        float s = g2[k] / sqrtf(v2[k] + 1e-5f);
        bf[k] = b2[k] * s + be2[k] - m2[k] * s;
    }
    for (int q = t; q < KD * HD; q += stride) {       // frag-linear W2fT hi/lo
        int g = q >> 9;
        int r = q & 511;
        int lane = r >> 3, idx = r & 7;
        int m = lane & 15, quad = lane >> 4;
        int k = g * 16 + m;
        int j = quad * 8 + idx;
        float s = g2[k] / sqrtf(v2[k] + 1e-5f);
        float v = W2[j * KD + k] * s;
        unsigned short hi, lo;
        bf16_split(v, hi, lo);
        ahi[q] = hi;
        alo[q] = lo;
    }
}

// ---------------------------------------------------------------------------
// out = x @ root + bias  (initializes all of d_out before edge atomics land)
// ---------------------------------------------------------------------------
__global__ void root_kernel(const float* __restrict__ x, const float* __restrict__ root,
                            const float* __restrict__ bias, float* __restrict__ out, int nN)
{
    int t = blockIdx.x * blockDim.x + threadIdx.x;
    if (t >= nN * OD) return;
    int o = t & (OD - 1);
    int n = t >> 5;
    const float* xr = x + (size_t)n * HD;
    float acc = bias[o];
#pragma unroll
    for (int i = 0; i < HD; ++i)
        acc = fmaf(xr[i], root[i * OD + o], acc);
    out[t] = acc;
}

// ---------------------------------------------------------------------------
// Fused edge kernel v5 (MFMA, rolled pipeline, LDS x-staging):
//  Phase 1: one edge/thread: load x[src] row into regs (early), compute
//           h = LReLU(ea@W1f+b1f), hi/lo split -> LDS (HPAD rows).
//  Frag read: B-frags (h) LDS->regs. Then h LDS region is DEAD; after a
//           barrier it is overlaid with xS[edge][i] (f32, XPAD rows).
//  Phase 2: rolled i-loop (unroll 1), depth-1 register rotation prefetch of
//           the 4 A-frag loads (global, L2-hot); x from LDS broadcast;
//           bias from LDS; 3 MFMAs per C (split-bf16); fused LReLU+contract.
//  Epilogue: 32 atomicAdd per edge.
//  LDS ~48.2 KB -> 3 blocks/CU.
// ---------------------------------------------------------------------------
__global__ __launch_bounds__(256, 3)
void edge_kernel(const float* __restrict__ x, const int* __restrict__ eidx,
                 const float* __restrict__ ea_g, const unsigned char* __restrict__ wsb,
                 float* __restrict__ out, int nE)
{
    // carved shared memory (overlay region first, 16B aligned)
    __shared__ __align__(16) unsigned char smem[EPB * HPAD * 2 * 2   // h hi+lo / xS
                                                + 2048                // w1t
                                                + 128                 // b1s
                                                + 4096                // bfS
                                                + 2048];              // src+dst
    unsigned short* hHi = (unsigned short*)smem;                      // [EPB][HPAD]
    unsigned short* hLo = hHi + EPB * HPAD;
    float*          xS  = (float*)smem;                               // overlay: [EPB][XPAD]
    float* w1t = (float*)(smem + EPB * HPAD * 4);
    float* b1s = w1t + 512;
    float* bfS = b1s + 32;
    int*  srcS = (int*)(bfS + KD);
    int*  dstS = srcS + EPB;

    const int t = threadIdx.x;
    const float* wsW1 = (const float*)(wsb);
    const float* wsB1 = (const float*)(wsb + 2048);
    const float* wsBf = (const float*)(wsb + 2176);
    const unsigned short* wsAhi = (const unsigned short*)(wsb + 6272);
    const unsigned short* wsAlo = (const unsigned short*)(wsb + 71808);

    // stage W1fT + b1f + bfold
    if (t < 128)      ((v4f*)w1t)[t] = ((const v4f*)wsW1)[t];
    else if (t < 136) ((v4f*)b1s)[t - 128] = ((const v4f*)wsB1)[t - 128];
    ((v4f*)bfS)[t] = ((const v4f*)wsBf)[t];

    int e = blockIdx.x * EPB + t;
    int ec = (e < nE) ? e : (nE - 1);
    int my_src = eidx[ec];
    srcS[t] = my_src;
    dstS[t] = eidx[nE + ec];

    // issue x-row load early (latency hides under layer-1 compute)
    const v4f* xrow_p = (const v4f*)(x + (size_t)my_src * HD);
    v4f xrow[8];
#pragma unroll
    for (int q = 0; q < 8; ++q) xrow[q] = xrow_p[q];

    const v4f* eap = (const v4f*)(ea_g + (size_t)ec * ED);
    v4f a0 = eap[0], a1 = eap[1], a2 = eap[2], a3 = eap[3];

    __syncthreads();   // (1) w1t/b1s ready

    // ---- layer 1 into registers ----
    float hreg[HD];
#pragma unroll
    for (int c = 0; c < HD; ++c) {
        const v4f* r4 = (const v4f*)(w1t + c * ED);
        v4f w0 = r4[0], w1 = r4[1], w2 = r4[2], w3 = r4[3];
        float acc = b1s[c];
        acc = fmaf(a0.x, w0.x, acc); acc = fmaf(a0.y, w0.y, acc);
        acc = fmaf(a0.z, w0.z, acc); acc = fmaf(a0.w, w0.w, acc);
        acc = fmaf(a1.x, w1.x, acc); acc = fmaf(a1.y, w1.y, acc);
        acc = fmaf(a1.z, w1.z, acc); acc = fmaf(a1.w, w1.w, acc);
        acc = fmaf(a2.x, w2.x, acc); acc = fmaf(a2.y, w2.y, acc);
        acc = fmaf(a2.z, w2.z, acc); acc = fmaf(a2.w, w2.w, acc);
        acc = fmaf(a3.x, w3.x, acc); acc = fmaf(a3.y, w3.y, acc);
        acc = fmaf(a3.z, w3.z, acc); acc = fmaf(a3.w, w3.w, acc);
        hreg[c] = fmaxf(acc, 0.01f * acc);
    }

    // ---- pack hi/lo, store to padded LDS rows ----
#pragma unroll
    for (int ch = 0; ch < 4; ++ch) {
        bf16x8 phi, plo;
#pragma unroll
        for (int u = 0; u < 8; ++u) {
            unsigned short hi, lo;
            bf16_split(hreg[ch * 8 + u], hi, lo);
            phi[u] = (short)hi;
            plo[u] = (short)lo;
        }
        *(bf16x8*)(hHi + t * HPAD + ch * 8) = phi;
        *(bf16x8*)(hLo + t * HPAD + ch * 8) = plo;
    }
    __syncthreads();   // (2) h ready

    // ---- B-frags LDS -> regs ----
    const int wave = t >> 6;
    const int lane = t & 63;
    const int n = lane & 15;       // C column = edge within tile
    const int quad = lane >> 4;
    const int ebase = wave * 64;   // wave's first edge in block

    bf16x8 bHi[TPW], bLo[TPW];
#pragma unroll
    for (int tt = 0; tt < TPW; ++tt) {
        int edge = ebase + tt * 16 + n;
        bHi[tt] = *(const bf16x8*)(hHi + edge * HPAD + quad * 8);
        bLo[tt] = *(const bf16x8*)(hLo + edge * HPAD + quad * 8);
    }

    int xdst[TPW];
    bool evalid[TPW];
    int xoff[TPW];
#pragma unroll
    for (int tt = 0; tt < TPW; ++tt) {
        int le = ebase + tt * 16 + n;
        evalid[tt] = (blockIdx.x * EPB + le) < nE;
        xdst[tt] = dstS[le];
        xoff[tt] = le * XPAD;
    }

    __syncthreads();   // (3) everyone done reading h LDS

    // ---- overlay: write x rows into xS ----
#pragma unroll
    for (int q = 0; q < 8; ++q) {
        v4f v = xrow[q];
        xS[t * XPAD + 4 * q + 0] = v.x;
        xS[t * XPAD + 4 * q + 1] = v.y;
        xS[t * XPAD + 4 * q + 2] = v.z;
        xS[t * XPAD + 4 * q + 3] = v.w;
    }
    __syncthreads();   // (4) xS ready

    f32x4 msg[TPW][2];
#pragma unroll
    for (int tt = 0; tt < TPW; ++tt) {
        msg[tt][0] = (f32x4){0.f, 0.f, 0.f, 0.f};
        msg[tt][1] = (f32x4){0.f, 0.f, 0.f, 0.f};
    }

    const unsigned short* pAhi = wsAhi + lane * 8;
    const unsigned short* pAlo = wsAlo + lane * 8;

    // prologue: A-frag loads for i=0
    bf16x8 cH0 = *(const bf16x8*)(pAhi + 0 * 512);
    bf16x8 cL0 = *(const bf16x8*)(pAlo + 0 * 512);
    bf16x8 cH1 = *(const bf16x8*)(pAhi + 1 * 512);
    bf16x8 cL1 = *(const bf16x8*)(pAlo + 1 * 512);

#pragma unroll 1
    for (int i = 0; i < HD; ++i) {
        // depth-1 prefetch, wrap-clamped (rolled loop: no spill blowup)
        const int gn = 2 * ((i + 1) & (HD - 1));
        bf16x8 nH0 = *(const bf16x8*)(pAhi + (size_t)gn * 512);
        bf16x8 nL0 = *(const bf16x8*)(pAlo + (size_t)gn * 512);
        bf16x8 nH1 = *(const bf16x8*)(pAhi + (size_t)(gn + 1) * 512);
        bf16x8 nL1 = *(const bf16x8*)(pAlo + (size_t)(gn + 1) * 512);

        f32x4 b0  = *(const f32x4*)(bfS + (2 * i) * 16 + quad * 4);
        f32x4 b1v = *(const f32x4*)(bfS + (2 * i + 1) * 16 + quad * 4);
        float xv[TPW];
#pragma unroll
        for (int tt = 0; tt < TPW; ++tt) xv[tt] = xS[xoff[tt] + i];

#pragma unroll
        for (int tt = 0; tt < TPW; ++tt) {
            f32x4 c0 = b0;
            c0 = __builtin_amdgcn_mfma_f32_16x16x32_bf16(cL0, bHi[tt], c0, 0, 0, 0);
            c0 = __builtin_amdgcn_mfma_f32_16x16x32_bf16(cH0, bLo[tt], c0, 0, 0, 0);
            c0 = __builtin_amdgcn_mfma_f32_16x16x32_bf16(cH0, bHi[tt], c0, 0, 0, 0);
            f32x4 c1 = b1v;
            c1 = __builtin_amdgcn_mfma_f32_16x16x32_bf16(cL1, bHi[tt], c1, 0, 0, 0);
            c1 = __builtin_amdgcn_mfma_f32_16x16x32_bf16(cH1, bLo[tt], c1, 0, 0, 0);
            c1 = __builtin_amdgcn_mfma_f32_16x16x32_bf16(cH1, bHi[tt], c1, 0, 0, 0);
            f32x4 w0 = __builtin_elementwise_max(c0, 0.01f * c0);   // LeakyReLU
            f32x4 w1 = __builtin_elementwise_max(c1, 0.01f * c1);
            f32x4 xs = {xv[tt], xv[tt], xv[tt], xv[tt]};
            msg[tt][0] = __builtin_elementwise_fma(xs, w0, msg[tt][0]);
            msg[tt][1] = __builtin_elementwise_fma(xs, w1, msg[tt][1]);
        }

        cH0 = nH0; cL0 = nL0; cH1 = nH1; cL1 = nL1;
    }

    // ---- scatter: out[dst][o], o = oh*16 + quad*4 + r ----
#pragma unroll
    for (int tt = 0; tt < TPW; ++tt) {
        if (!evalid[tt]) continue;
        float* op = out + (size_t)xdst[tt] * OD;
#pragma unroll
        for (int oh = 0; oh < 2; ++oh)
#pragma unroll
            for (int r = 0; r < 4; ++r)
                atomicAdd(op + oh * 16 + quad * 4 + r, msg[tt][oh][r]);
    }
}

// ---------------------------------------------------------------------------
// Fallback (ws too small): correctness path only (VALU, raw weights).
// ---------------------------------------------------------------------------
__global__ __launch_bounds__(64)
void edge_kernel_raw(const float* __restrict__ x, const int* __restrict__ eidx,
                     const float* __restrict__ ea_g,
                     const float* __restrict__ W1, const float* __restrict__ b1,
                     const float* __restrict__ g1, const float* __restrict__ be1,
                     const float* __restrict__ m1, const float* __restrict__ v1,
                     const float* __restrict__ W2, const float* __restrict__ b2,
                     const float* __restrict__ g2, const float* __restrict__ be2,
                     const float* __restrict__ m2, const float* __restrict__ v2,
                     float* __restrict__ out, int nE)
{
    int e = blockIdx.x * 64 + threadIdx.x;
    if (e >= nE) return;
    const int obase = blockIdx.y * 16;

    int src = eidx[e];
    int dst = eidx[nE + e];

    float ea[ED];
#pragma unroll
    for (int j = 0; j < ED; ++j) ea[j] = ea_g[(size_t)e * ED + j];

    float h[HD];
#pragma unroll
    for (int c = 0; c < HD; ++c) {
        float acc = b1[c];
#pragma unroll
        for (int j = 0; j < ED; ++j) acc = fmaf(ea[j], W1[j * HD + c], acc);
        float s = g1[c] / sqrtf(v1[c] + 1e-5f);
        acc = (acc - m1[c]) * s + be1[c];
        h[c] = fmaxf(acc, 0.01f * acc);
    }

    float msg[16];
#pragma unroll
    for (int o = 0; o < 16; ++o) msg[o] = 0.f;

    const float* xj = x + (size_t)src * HD;
    for (int i = 0; i < HD; ++i) {
        float xv = xj[i];
#pragma unroll
        for (int oo = 0; oo < 16; ++oo) {
            int k = i * OD + obase + oo;
            float acc = b2[k];
#pragma unroll
            for (int j = 0; j < HD; ++j) acc = fmaf(h[j], W2[j * KD + k], acc);
            float s = g2[k] / sqrtf(v2[k] + 1e-5f);
            acc = (acc - m2[k]) * s + be2[k];
            float w = fmaxf(acc, 0.01f * acc);
            msg[oo] = fmaf(xv, w, msg[oo]);
        }
    }

    float* op = out + (size_t)dst * OD + obase;
#pragma unroll
    for (int oo = 0; oo < 16; ++oo) atomicAdd(op + oo, msg[oo]);
}

// ---------------------------------------------------------------------------
extern "C" void kernel_launch(void* const* d_in, const int* in_sizes, int n_in,
                              void* d_out, int out_size, void* d_ws, size_t ws_size,
                              hipStream_t stream)
{
    const float* x    = (const float*)d_in[0];
    const int*   eidx = (const int*)  d_in[1];
    const float* ea   = (const float*)d_in[2];
    // d_in[3] = batch (unused)
    const float* W1   = (const float*)d_in[4];
    const float* b1   = (const float*)d_in[5];
    const float* g1   = (const float*)d_in[6];
    const float* be1  = (const float*)d_in[7];
    const float* m1   = (const float*)d_in[8];
    const float* v1   = (const float*)d_in[9];
    const float* W2   = (const float*)d_in[10];
    const float* b2   = (const float*)d_in[11];
    const float* g2   = (const float*)d_in[12];
    const float* be2  = (const float*)d_in[13];
    const float* m2   = (const float*)d_in[14];
    const float* v2   = (const float*)d_in[15];
    const float* root = (const float*)d_in[16];
    const float* bias = (const float*)d_in[17];
    float* out = (float*)d_out;

    int nN = in_sizes[0] / HD;
    int nE = in_sizes[2] / ED;

    root_kernel<<<dim3((nN * OD + 255) / 256), 256, 0, stream>>>(x, root, bias, out, nN);

    if (ws_size >= WS_BYTES) {
        unsigned char* wsb = (unsigned char*)d_ws;
        prep_kernel<<<128, 256, 0, stream>>>(W1, b1, g1, be1, m1, v1,
                                             W2, b2, g2, be2, m2, v2, wsb);
        int nblk = (nE + EPB - 1) / EPB;
        edge_kernel<<<dim3(nblk), 256, 0, stream>>>(x, eidx, ea, wsb, out, nE);
    } else {
        edge_kernel_raw<<<dim3((nE + 63) / 64, 2), 64, 0, stream>>>(
            x, eidx, ea, W1, b1, g1, be1, m1, v1,
            W2, b2, g2, be2, m2, v2, out, nE);
    }
}

// Round 6
// 227.269 us; speedup vs baseline: 2.7483x; 1.1027x over previous
//
#include <hip/hip_runtime.h>
#include <math.h>

// Problem dims (fixed by the reference)
#define ED 16      // EDGE_DIM
#define HD 32      // HIDDEN (== NODE_DIM == in_channels)
#define OD 32      // OUT_DIM
#define KD 1024    // HD*OD
#define EPB 256    // edges per block
#define TPW 4      // 16-edge tiles per wave
#define HPAD 40    // padded LDS row stride (halfwords) for h (16B-aligned rows)
#define XPAD 33    // padded LDS row stride (floats) for x rows (conflict-free)

typedef float  f32x4  __attribute__((ext_vector_type(4)));
typedef float  v4f    __attribute__((ext_vector_type(4)));
typedef short  bf16x8 __attribute__((ext_vector_type(8)));

// Workspace layout (byte offsets; all 16B aligned)
//  [0)      W1fT   512 f32   [c][j] transposed, bn1-scaled
//  [2048)   b1f     32 f32
//  [2176)   bfold 1024 f32   folded layer-2 bias, natural k order
//  [6272)   wsAhi 32768 bf16 W2fT hi, frag-linear: q = g*512 + lane*8 + idx
//                             -> value W2fT[k=g*16+(lane&15)][j=(lane>>4)*8+idx]
//  [71808)  wsAlo 32768 bf16 W2fT lo, same order
constexpr size_t WS_BYTES = 137344;

__device__ inline void bf16_split(float v, unsigned short& hi, unsigned short& lo) {
    unsigned int b = __float_as_uint(v);
    hi = (unsigned short)(b >> 16);
    float hif = __uint_as_float((unsigned int)hi << 16);
    float lof = v - hif;
    lo = (unsigned short)(__float_as_uint(lof) >> 16);
}

// ---------------------------------------------------------------------------
// Prep v2: fold BN into weights/biases. Big W2 loop traverses in SOURCE-linear
// order (coalesced reads); destination writes are scattered 2B fire-and-forget.
// ---------------------------------------------------------------------------
__global__ void prep_kernel(const float* __restrict__ W1, const float* __restrict__ b1,
                            const float* __restrict__ g1, const float* __restrict__ be1,
                            const float* __restrict__ m1, const float* __restrict__ v1,
                            const float* __restrict__ W2, const float* __restrict__ b2,
                            const float* __restrict__ g2, const float* __restrict__ be2,
                            const float* __restrict__ m2, const float* __restrict__ v2,
                            unsigned char* __restrict__ wsb)
{
    float* w1t = (float*)(wsb);
    float* b1f = (float*)(wsb + 2048);
    float* bf  = (float*)(wsb + 2176);
    unsigned short* ahi = (unsigned short*)(wsb + 6272);
    unsigned short* alo = (unsigned short*)(wsb + 71808);

    int t = blockIdx.x * blockDim.x + threadIdx.x;
    int stride = gridDim.x * blockDim.x;

    for (int q = t; q < HD * ED; q += stride) {       // W1fT [c][j]
        int c = q >> 4, j = q & 15;
        float s = g1[c] / sqrtf(v1[c] + 1e-5f);
        w1t[q] = W1[j * HD + c] * s;
    }
    for (int c = t; c < HD; c += stride) {
        float s = g1[c] / sqrtf(v1[c] + 1e-5f);
        b1f[c] = b1[c] * s + be1[c] - m1[c] * s;
    }
    for (int k = t; k < KD; k += stride) {
        float s = g2[k] / sqrtf(v2[k] + 1e-5f);
        bf[k] = b2[k] * s + be2[k] - m2[k] * s;
    }
    // p = j*KD + k : coalesced read of W2 and g2/v2
    for (int p = t; p < KD * HD; p += stride) {
        int j = p >> 10, k = p & 1023;
        float s = g2[k] / sqrtf(v2[k] + 1e-5f);
        float v = W2[p] * s;
        int g = k >> 4, m = k & 15;
        int quad = j >> 3, idx = j & 7;
        int q = g * 512 + (quad * 16 + m) * 8 + idx;  // frag-linear dest
        unsigned short hi, lo;
        bf16_split(v, hi, lo);
        ahi[q] = hi;
        alo[q] = lo;
    }
}

// ---------------------------------------------------------------------------
// Root v2: out = x @ root + bias, LDS-staged (root + 8 x-rows per block).
// Also initializes all of d_out before edge atomics land.
// ---------------------------------------------------------------------------
__global__ __launch_bounds__(256)
void root_kernel(const float* __restrict__ x, const float* __restrict__ root,
                 const float* __restrict__ bias, float* __restrict__ out, int nN)
{
    __shared__ __align__(16) float rootS[HD * OD];   // 4 KB
    __shared__ __align__(16) float biasS[OD];
    __shared__ float xsh[8][XPAD];

    const int t = threadIdx.x;
    ((v4f*)rootS)[t] = ((const v4f*)root)[t];        // 256 v4f = 1024 f
    if (t < 8) ((v4f*)biasS)[t] = ((const v4f*)bias)[t];

    const int nodeBase = blockIdx.x * 8;
    if (t < 64) {
        int nl = t >> 3, q = t & 7;
        int node = nodeBase + nl;
        if (node >= nN) node = nN - 1;
        v4f v = ((const v4f*)(x + (size_t)node * HD))[q];
        xsh[nl][4 * q + 0] = v.x;
        xsh[nl][4 * q + 1] = v.y;
        xsh[nl][4 * q + 2] = v.z;
        xsh[nl][4 * q + 3] = v.w;
    }
    __syncthreads();

    const int nl = t >> 5, o = t & 31;
    const int node = nodeBase + nl;
    if (node >= nN) return;
    float acc = biasS[o];
#pragma unroll
    for (int i = 0; i < HD; ++i)
        acc = fmaf(xsh[nl][i], rootS[i * OD + o], acc);
    out[(size_t)node * OD + o] = acc;
}

// ---------------------------------------------------------------------------
// Fused edge kernel v6 (MFMA + depth-2 ring prefetch + nt streaming loads):
//  Phase 1: one edge/thread: x-row load early, h = LReLU(ea@W1f+b1f),
//           hi/lo split -> LDS (HPAD rows). ea/eidx use non-temporal loads
//           so the read-once streams don't evict the hot weight set from L2.
//  Phase 2: rolled outer loop (8), inner unrolled x4; 4-slot ring of A-frag
//           loads with depth-2 prefetch (issue at u, consume at u+2 => ~600cy
//           in flight, per-register vmcnt keeps 8-12 loads outstanding).
//           x from LDS broadcast (overlay of dead h region), bias from LDS,
//           3 MFMAs per C (split-bf16), fused LReLU + contraction.
//  Epilogue: 32 atomicAdd per edge.
//  LDS ~48.2 KB -> 3 blocks/CU; VGPR ~112 (ring 64 + frags/acc) < 168 cap.
// ---------------------------------------------------------------------------
__global__ __launch_bounds__(256, 3)
void edge_kernel(const float* __restrict__ x, const int* __restrict__ eidx,
                 const float* __restrict__ ea_g, const unsigned char* __restrict__ wsb,
                 float* __restrict__ out, int nE)
{
    __shared__ __align__(16) unsigned char smem[EPB * HPAD * 2 * 2   // h hi+lo / xS
                                                + 2048                // w1t
                                                + 128                 // b1s
                                                + 4096                // bfS
                                                + 2048];              // src+dst
    unsigned short* hHi = (unsigned short*)smem;                      // [EPB][HPAD]
    unsigned short* hLo = hHi + EPB * HPAD;
    float*          xS  = (float*)smem;                               // overlay: [EPB][XPAD]
    float* w1t = (float*)(smem + EPB * HPAD * 4);
    float* b1s = w1t + 512;
    float* bfS = b1s + 32;
    int*  srcS = (int*)(bfS + KD);
    int*  dstS = srcS + EPB;

    const int t = threadIdx.x;
    const float* wsW1 = (const float*)(wsb);
    const float* wsB1 = (const float*)(wsb + 2048);
    const float* wsBf = (const float*)(wsb + 2176);
    const unsigned short* wsAhi = (const unsigned short*)(wsb + 6272);
    const unsigned short* wsAlo = (const unsigned short*)(wsb + 71808);

    // stage W1fT + b1f + bfold
    if (t < 128)      ((v4f*)w1t)[t] = ((const v4f*)wsW1)[t];
    else if (t < 136) ((v4f*)b1s)[t - 128] = ((const v4f*)wsB1)[t - 136 + 8];  // 8 v4f
    ((v4f*)bfS)[t] = ((const v4f*)wsBf)[t];

    int e = blockIdx.x * EPB + t;
    int ec = (e < nE) ? e : (nE - 1);
    // non-temporal: eidx is a read-once stream
    int my_src = __builtin_nontemporal_load(eidx + ec);
    int my_dst = __builtin_nontemporal_load(eidx + nE + ec);
    srcS[t] = my_src;
    dstS[t] = my_dst;

    // x-row load early (cached: x rows have ~4x reuse across edges)
    const v4f* xrow_p = (const v4f*)(x + (size_t)my_src * HD);
    v4f xrow[8];
#pragma unroll
    for (int q = 0; q < 8; ++q) xrow[q] = xrow_p[q];

    // non-temporal: ea is a read-once stream
    const v4f* eap = (const v4f*)(ea_g + (size_t)ec * ED);
    v4f a0 = __builtin_nontemporal_load(eap + 0);
    v4f a1 = __builtin_nontemporal_load(eap + 1);
    v4f a2 = __builtin_nontemporal_load(eap + 2);
    v4f a3 = __builtin_nontemporal_load(eap + 3);

    __syncthreads();   // (1) w1t/b1s ready

    // ---- layer 1 into registers ----
    float hreg[HD];
#pragma unroll
    for (int c = 0; c < HD; ++c) {
        const v4f* r4 = (const v4f*)(w1t + c * ED);
        v4f w0 = r4[0], w1 = r4[1], w2 = r4[2], w3 = r4[3];
        float acc = b1s[c];
        acc = fmaf(a0.x, w0.x, acc); acc = fmaf(a0.y, w0.y, acc);
        acc = fmaf(a0.z, w0.z, acc); acc = fmaf(a0.w, w0.w, acc);
        acc = fmaf(a1.x, w1.x, acc); acc = fmaf(a1.y, w1.y, acc);
        acc = fmaf(a1.z, w1.z, acc); acc = fmaf(a1.w, w1.w, acc);
        acc = fmaf(a2.x, w2.x, acc); acc = fmaf(a2.y, w2.y, acc);
        acc = fmaf(a2.z, w2.z, acc); acc = fmaf(a2.w, w2.w, acc);
        acc = fmaf(a3.x, w3.x, acc); acc = fmaf(a3.y, w3.y, acc);
        acc = fmaf(a3.z, w3.z, acc); acc = fmaf(a3.w, w3.w, acc);
        hreg[c] = fmaxf(acc, 0.01f * acc);
    }

    // ---- pack hi/lo, store to padded LDS rows ----
#pragma unroll
    for (int ch = 0; ch < 4; ++ch) {
        bf16x8 phi, plo;
#pragma unroll
        for (int u = 0; u < 8; ++u) {
            unsigned short hi, lo;
            bf16_split(hreg[ch * 8 + u], hi, lo);
            phi[u] = (short)hi;
            plo[u] = (short)lo;
        }
        *(bf16x8*)(hHi + t * HPAD + ch * 8) = phi;
        *(bf16x8*)(hLo + t * HPAD + ch * 8) = plo;
    }
    __syncthreads();   // (2) h ready

    // ---- B-frags LDS -> regs ----
    const int wave = t >> 6;
    const int lane = t & 63;
    const int n = lane & 15;       // C column = edge within tile
    const int quad = lane >> 4;
    const int ebase = wave * 64;   // wave's first edge in block

    bf16x8 bHi[TPW], bLo[TPW];
#pragma unroll
    for (int tt = 0; tt < TPW; ++tt) {
        int edge = ebase + tt * 16 + n;
        bHi[tt] = *(const bf16x8*)(hHi + edge * HPAD + quad * 8);
        bLo[tt] = *(const bf16x8*)(hLo + edge * HPAD + quad * 8);
    }

    int xdst[TPW];
    bool evalid[TPW];
    int xoff[TPW];
#pragma unroll
    for (int tt = 0; tt < TPW; ++tt) {
        int le = ebase + tt * 16 + n;
        evalid[tt] = (blockIdx.x * EPB + le) < nE;
        xdst[tt] = dstS[le];
        xoff[tt] = le * XPAD;
    }

    __syncthreads();   // (3) everyone done reading h LDS

    // ---- overlay: write x rows into xS ----
#pragma unroll
    for (int q = 0; q < 8; ++q) {
        v4f v = xrow[q];
        xS[t * XPAD + 4 * q + 0] = v.x;
        xS[t * XPAD + 4 * q + 1] = v.y;
        xS[t * XPAD + 4 * q + 2] = v.z;
        xS[t * XPAD + 4 * q + 3] = v.w;
    }
    __syncthreads();   // (4) xS ready

    f32x4 msg[TPW][2];
#pragma unroll
    for (int tt = 0; tt < TPW; ++tt) {
        msg[tt][0] = (f32x4){0.f, 0.f, 0.f, 0.f};
        msg[tt][1] = (f32x4){0.f, 0.f, 0.f, 0.f};
    }

    const unsigned short* pAhi = wsAhi + lane * 8;
    const unsigned short* pAlo = wsAlo + lane * 8;

    // ---- 4-slot ring, depth-2 prefetch ----
    bf16x8 rH0[4], rL0[4], rH1[4], rL1[4];
#pragma unroll
    for (int p = 0; p < 2; ++p) {     // prologue: slots 0,1 (i=0,1)
        const int g = 2 * p;
        rH0[p] = *(const bf16x8*)(pAhi + (size_t)g * 512);
        rL0[p] = *(const bf16x8*)(pAlo + (size_t)g * 512);
        rH1[p] = *(const bf16x8*)(pAhi + (size_t)(g + 1) * 512);
        rL1[p] = *(const bf16x8*)(pAlo + (size_t)(g + 1) * 512);
    }

#pragma unroll 1
    for (int io = 0; io < HD / 4; ++io) {
#pragma unroll
        for (int u = 0; u < 4; ++u) {
            const int i = io * 4 + u;
            const int slot = u;                 // (io*4+u) & 3 == u
            const int pslot = (u + 2) & 3;
            const int pig = ((i + 2) & (HD - 1)) * 2;   // groups for i+2
            // issue depth-2 prefetch first (consumed 2 sub-iters later)
            rH0[pslot] = *(const bf16x8*)(pAhi + (size_t)pig * 512);
            rL0[pslot] = *(const bf16x8*)(pAlo + (size_t)pig * 512);
            rH1[pslot] = *(const bf16x8*)(pAhi + (size_t)(pig + 1) * 512);
            rL1[pslot] = *(const bf16x8*)(pAlo + (size_t)(pig + 1) * 512);

            f32x4 b0  = *(const f32x4*)(bfS + (2 * i) * 16 + quad * 4);
            f32x4 b1v = *(const f32x4*)(bfS + (2 * i + 1) * 16 + quad * 4);
            float xv[TPW];
#pragma unroll
            for (int tt = 0; tt < TPW; ++tt) xv[tt] = xS[xoff[tt] + i];

            const bf16x8 cH0 = rH0[slot], cL0 = rL0[slot];
            const bf16x8 cH1 = rH1[slot], cL1 = rL1[slot];
#pragma unroll
            for (int tt = 0; tt < TPW; ++tt) {
                f32x4 c0 = b0;
                c0 = __builtin_amdgcn_mfma_f32_16x16x32_bf16(cL0, bHi[tt], c0, 0, 0, 0);
                c0 = __builtin_amdgcn_mfma_f32_16x16x32_bf16(cH0, bLo[tt], c0, 0, 0, 0);
                c0 = __builtin_amdgcn_mfma_f32_16x16x32_bf16(cH0, bHi[tt], c0, 0, 0, 0);
                f32x4 c1 = b1v;
                c1 = __builtin_amdgcn_mfma_f32_16x16x32_bf16(cL1, bHi[tt], c1, 0, 0, 0);
                c1 = __builtin_amdgcn_mfma_f32_16x16x32_bf16(cH1, bLo[tt], c1, 0, 0, 0);
                c1 = __builtin_amdgcn_mfma_f32_16x16x32_bf16(cH1, bHi[tt], c1, 0, 0, 0);
                f32x4 w0 = __builtin_elementwise_max(c0, 0.01f * c0);   // LeakyReLU
                f32x4 w1 = __builtin_elementwise_max(c1, 0.01f * c1);
                f32x4 xs = {xv[tt], xv[tt], xv[tt], xv[tt]};
                msg[tt][0] = __builtin_elementwise_fma(xs, w0, msg[tt][0]);
                msg[tt][1] = __builtin_elementwise_fma(xs, w1, msg[tt][1]);
            }
        }
    }

    // ---- scatter: out[dst][o], o = oh*16 + quad*4 + r ----
#pragma unroll
    for (int tt = 0; tt < TPW; ++tt) {
        if (!evalid[tt]) continue;
        float* op = out + (size_t)xdst[tt] * OD;
#pragma unroll
        for (int oh = 0; oh < 2; ++oh)
#pragma unroll
            for (int r = 0; r < 4; ++r)
                atomicAdd(op + oh * 16 + quad * 4 + r, msg[tt][oh][r]);
    }
}

// ---------------------------------------------------------------------------
// Fallback (ws too small): correctness path only (VALU, raw weights).
// ---------------------------------------------------------------------------
__global__ __launch_bounds__(64)
void edge_kernel_raw(const float* __restrict__ x, const int* __restrict__ eidx,
                     const float* __restrict__ ea_g,
                     const float* __restrict__ W1, const float* __restrict__ b1,
                     const float* __restrict__ g1, const float* __restrict__ be1,
                     const float* __restrict__ m1, const float* __restrict__ v1,
                     const float* __restrict__ W2, const float* __restrict__ b2,
                     const float* __restrict__ g2, const float* __restrict__ be2,
                     const float* __restrict__ m2, const float* __restrict__ v2,
                     float* __restrict__ out, int nE)
{
    int e = blockIdx.x * 64 + threadIdx.x;
    if (e >= nE) return;
    const int obase = blockIdx.y * 16;

    int src = eidx[e];
    int dst = eidx[nE + e];

    float ea[ED];
#pragma unroll
    for (int j = 0; j < ED; ++j) ea[j] = ea_g[(size_t)e * ED + j];

    float h[HD];
#pragma unroll
    for (int c = 0; c < HD; ++c) {
        float acc = b1[c];
#pragma unroll
        for (int j = 0; j < ED; ++j) acc = fmaf(ea[j], W1[j * HD + c], acc);
        float s = g1[c] / sqrtf(v1[c] + 1e-5f);
        acc = (acc - m1[c]) * s + be1[c];
        h[c] = fmaxf(acc, 0.01f * acc);
    }

    float msg[16];
#pragma unroll
    for (int o = 0; o < 16; ++o) msg[o] = 0.f;

    const float* xj = x + (size_t)src * HD;
    for (int i = 0; i < HD; ++i) {
        float xv = xj[i];
#pragma unroll
        for (int oo = 0; oo < 16; ++oo) {
            int k = i * OD + obase + oo;
            float acc = b2[k];
#pragma unroll
            for (int j = 0; j < HD; ++j) acc = fmaf(h[j], W2[j * KD + k], acc);
            float s = g2[k] / sqrtf(v2[k] + 1e-5f);
            acc = (acc - m2[k]) * s + be2[k];
            float w = fmaxf(acc, 0.01f * acc);
            msg[oo] = fmaf(xv, w, msg[oo]);
        }
    }

    float* op = out + (size_t)dst * OD + obase;
#pragma unroll
    for (int oo = 0; oo < 16; ++oo) atomicAdd(op + oo, msg[oo]);
}

// ---------------------------------------------------------------------------
extern "C" void kernel_launch(void* const* d_in, const int* in_sizes, int n_in,
                              void* d_out, int out_size, void* d_ws, size_t ws_size,
                              hipStream_t stream)
{
    const float* x    = (const float*)d_in[0];
    const int*   eidx = (const int*)  d_in[1];
    const float* ea   = (const float*)d_in[2];
    // d_in[3] = batch (unused)
    const float* W1   = (const float*)d_in[4];
    const float* b1   = (const float*)d_in[5];
    const float* g1   = (const float*)d_in[6];
    const float* be1  = (const float*)d_in[7];
    const float* m1   = (const float*)d_in[8];
    const float* v1   = (const float*)d_in[9];
    const float* W2   = (const float*)d_in[10];
    const float* b2   = (const float*)d_in[11];
    const float* g2   = (const float*)d_in[12];
    const float* be2  = (const float*)d_in[13];
    const float* m2   = (const float*)d_in[14];
    const float* v2   = (const float*)d_in[15];
    const float* root = (const float*)d_in[16];
    const float* bias = (const float*)d_in[17];
    float* out = (float*)d_out;

    int nN = in_sizes[0] / HD;
    int nE = in_sizes[2] / ED;

    root_kernel<<<dim3((nN + 7) / 8), 256, 0, stream>>>(x, root, bias, out, nN);

    if (ws_size >= WS_BYTES) {
        unsigned char* wsb = (unsigned char*)d_ws;
        prep_kernel<<<128, 256, 0, stream>>>(W1, b1, g1, be1, m1, v1,
                                             W2, b2, g2, be2, m2, v2, wsb);
        int nblk = (nE + EPB - 1) / EPB;
        edge_kernel<<<dim3(nblk), 256, 0, stream>>>(x, eidx, ea, wsb, out, nE);
    } else {
        edge_kernel_raw<<<dim3((nE + 63) / 64, 2), 64, 0, stream>>>(
            x, eidx, ea, W1, b1, g1, be1, m1, v1,
            W2, b2, g2, be2, m2, v2, out, nE);
    }
}